// Round 8
// baseline (284.374 us; speedup 1.0000x reference)
//
#include <hip/hip_runtime.h>
#include <math.h>

// Problem constants (x: [4, 64, 384, 384] fp32)
#define QLS_T    256             // B*C = 4*64, sequential scan axis
#define QLS_HW   (384 * 384)     // independent spatial locations (147456)
#define QLS_HW4  (QLS_HW / 4)    // float4 granularity (36864)
#define CHUNK    16              // parallel t-chunks (re-associated scan)
#define TPC      (QLS_T / CHUNK) // 16 planes per chunk
#define TILES    36              // location tiles: 36 x 4096 = 147456
#define TILE_LOC 4096            // locations per tile -> 16KB contiguous span

// Quantizer constants from the reference
#define Q_SCALE      16.0f
#define INV_Q_SCALE  (1.0f / 16.0f)
#define QMAXF        7.9375f
#define QMINF        (-8.0f)
#define LUT_IN_SCALE 4096.0f
#define LUT_IN_MAX   32767.0f
#define INV_LUT_OUT  (1.0f / 65536.0f)

// log1p(exp(-d)) = log2(1 + 2^(-d*log2e)) * ln2, on raw v_exp_f32/v_log_f32.
#define NEG_LOG2E_DIV (-1.4426950408889634f / 4096.0f)
#define LN2_X_65536   45426.09375f

// Native clang vector type (HIP float4 is rejected by nontemporal builtin).
typedef float f32x4 __attribute__((ext_vector_type(4)));

__device__ __forceinline__ float qls_step(float s, float v) {
    float diff = fabsf(s - v);
    float d_int = fminf(floorf(diff * LUT_IN_SCALE), LUT_IN_MAX);
    float e  = __builtin_amdgcn_exp2f(d_int * NEG_LOG2E_DIV);
    float lu = rintf(__builtin_amdgcn_logf(1.0f + e) * LN2_X_65536) * INV_LUT_OUT;
    s = fmaxf(s, v) + lu;
    return fminf(fmaxf(s, QMINF), QMAXF);
}

// ---------------- K1: scan partials, TIME-CLUSTERED 16KB bursts ----------
// R10 theory: DRAM row efficiency needs >=16KB contiguous arriving TOGETHER
// (channel interleave 256B-1KB, row ~1KB -> a row's granules are spread
// over a 16KB address window). R9's 16KB spans were issued by 16 free-
// running waves that drift apart -> degenerated to scattered 1KB requests
// (the invariant of every ~3TB/s variant; the 6.6TB/s fill and 6.3TB/s
// copy both present monotone contiguous streams). Fix: __syncthreads()
// every iteration pins all 16 waves to the same pair of planes, so each
// block emits intact 2x16KB contiguous bursts. 576 blocks = 2.25/CU
// stagger to cover the barrier's vmcnt drain.
__global__ __launch_bounds__(1024) void qls_k1_scan(
    const float* __restrict__ x, float* __restrict__ part) {
    const int c    = blockIdx.x / TILES;                 // t-chunk, 0..15
    const int tile = blockIdx.x % TILES;                 // location tile, 0..35
    const int loc  = tile * TILE_LOC + threadIdx.x * 4;  // 4 consecutive locs
    const float* xp = x + (size_t)c * TPC * QLS_HW + loc;

    float s0 = QMINF, s1 = QMINF, s2 = QMINF, s3 = QMINF;
    #pragma unroll
    for (int k = 0; k < TPC; k += 2) {
        // Two 16KB plane-spans issued back-to-back by the whole block.
        f32x4 v0 = *reinterpret_cast<const f32x4*>(xp + (size_t)k * QLS_HW);
        f32x4 v1 = *reinterpret_cast<const f32x4*>(xp + (size_t)(k + 1) * QLS_HW);
        s0 = qls_step(s0, v0.x); s1 = qls_step(s1, v0.y);
        s2 = qls_step(s2, v0.z); s3 = qls_step(s3, v0.w);
        s0 = qls_step(s0, v1.x); s1 = qls_step(s1, v1.y);
        s2 = qls_step(s2, v1.z); s3 = qls_step(s3, v1.w);
        __syncthreads();   // keep all 16 waves on the same planes
    }
    f32x4 sv; sv.x = s0; sv.y = s1; sv.z = s2; sv.w = s3;
    // plain store: partials stay L2/L3-resident for K2
    *reinterpret_cast<f32x4*>(part + (size_t)c * QLS_HW + loc) = sv;
}

// ---------------- K2: merge 16 partials per location (t-order) -----------
// 9.4MB working set, cache-hot from K1. Same c-ascending order as R8/R9.
__global__ __launch_bounds__(256) void qls_k2_merge(
    const float* __restrict__ part, float* __restrict__ sbuf) {
    const int loc = (blockIdx.x * 256 + threadIdx.x) * 4;
    f32x4 t4 = *reinterpret_cast<const f32x4*>(part + loc);
    float t0 = t4.x, t1 = t4.y, t2 = t4.z, t3 = t4.w;
    #pragma unroll
    for (int c = 1; c < CHUNK; ++c) {
        f32x4 p4 = *reinterpret_cast<const f32x4*>(part + (size_t)c * QLS_HW + loc);
        t0 = qls_step(t0, p4.x); t1 = qls_step(t1, p4.y);
        t2 = qls_step(t2, p4.z); t3 = qls_step(t3, p4.w);
    }
    f32x4 sv; sv.x = t0; sv.y = t1; sv.z = t2; sv.w = t3;
    *reinterpret_cast<f32x4*>(sbuf + loc) = sv;
}

// ---------------- K3: output, same span+barrier discipline ---------------
// R9's K3 interleaved 4 planes per thread at 1KB granularity -> scattered.
// Here each block owns (plane-group, tile) and emits per iteration:
// 2x16KB contiguous reads of x (L3-warm from K1) + 2x16KB contiguous NT
// writes of out, then barrier-aligns the waves.
__global__ __launch_bounds__(1024) void qls_k3_out(
    const float* __restrict__ x, const float* __restrict__ sbuf,
    float* __restrict__ out) {
    const int pg   = blockIdx.x / TILES;                 // plane group, 0..15
    const int tile = blockIdx.x % TILES;
    const int loc  = tile * TILE_LOC + threadIdx.x * 4;
    const size_t base = (size_t)pg * TPC * QLS_HW + loc;

    const f32x4 s4 = *reinterpret_cast<const f32x4*>(sbuf + loc);

    #pragma unroll
    for (int k = 0; k < TPC; k += 2) {
        f32x4 v0 = *reinterpret_cast<const f32x4*>(x + base + (size_t)k * QLS_HW);
        f32x4 v1 = *reinterpret_cast<const f32x4*>(x + base + (size_t)(k + 1) * QLS_HW);
        f32x4 q0, q1;
        q0.x = fminf(fmaxf(rintf((v0.x - s4.x) * Q_SCALE), -128.0f), 127.0f) * INV_Q_SCALE;
        q0.y = fminf(fmaxf(rintf((v0.y - s4.y) * Q_SCALE), -128.0f), 127.0f) * INV_Q_SCALE;
        q0.z = fminf(fmaxf(rintf((v0.z - s4.z) * Q_SCALE), -128.0f), 127.0f) * INV_Q_SCALE;
        q0.w = fminf(fmaxf(rintf((v0.w - s4.w) * Q_SCALE), -128.0f), 127.0f) * INV_Q_SCALE;
        q1.x = fminf(fmaxf(rintf((v1.x - s4.x) * Q_SCALE), -128.0f), 127.0f) * INV_Q_SCALE;
        q1.y = fminf(fmaxf(rintf((v1.y - s4.y) * Q_SCALE), -128.0f), 127.0f) * INV_Q_SCALE;
        q1.z = fminf(fmaxf(rintf((v1.z - s4.z) * Q_SCALE), -128.0f), 127.0f) * INV_Q_SCALE;
        q1.w = fminf(fmaxf(rintf((v1.w - s4.w) * Q_SCALE), -128.0f), 127.0f) * INV_Q_SCALE;
        __builtin_nontemporal_store(q0, reinterpret_cast<f32x4*>(out + base + (size_t)k * QLS_HW));
        __builtin_nontemporal_store(q1, reinterpret_cast<f32x4*>(out + base + (size_t)(k + 1) * QLS_HW));
        __syncthreads();   // keep the block's write bursts intact
    }
}

// ---------------- Fallback: R7 chunked fused kernel (97us, best) ---------
__global__ __launch_bounds__(512, 4) void qls_fused_kernel(
    const float* __restrict__ x, float* __restrict__ out) {
    const int lane  = threadIdx.x & 63;
    const int chunk = threadIdx.x >> 6;               // 0..7
    const int loc   = blockIdx.x * 64 + lane;
    const size_t base = (size_t)loc + (size_t)chunk * 32 * QLS_HW;
    const float* xp = x + base;

    float v[32];
    #pragma unroll
    for (int k = 0; k < 32; ++k) v[k] = xp[(size_t)k * QLS_HW];

    float s = QMINF;
    #pragma unroll
    for (int k = 0; k < 32; ++k) s = qls_step(s, v[k]);

    __shared__ float part[8][64];
    part[chunk][lane] = s;
    __syncthreads();

    float tot = part[0][lane];
    #pragma unroll
    for (int c = 1; c < 8; ++c) tot = qls_step(tot, part[c][lane]);

    float* op = out + base;
    #pragma unroll
    for (int k = 0; k < 32; ++k) {
        float q = fminf(fmaxf(rintf((v[k] - tot) * Q_SCALE), -128.0f), 127.0f);
        __builtin_nontemporal_store(q * INV_Q_SCALE, op + (size_t)k * QLS_HW);
    }
}

extern "C" void kernel_launch(void* const* d_in, const int* in_sizes, int n_in,
                              void* d_out, int out_size, void* d_ws, size_t ws_size,
                              hipStream_t stream) {
    const float* x = (const float*)d_in[0];
    float* out = (float*)d_out;
    const size_t part_bytes = (size_t)CHUNK * QLS_HW * sizeof(float);  // 9.44 MB
    const size_t s_bytes    = (size_t)QLS_HW * sizeof(float);          // 576 KB

    if (d_ws != nullptr && ws_size >= part_bytes + s_bytes) {
        float* part = (float*)d_ws;
        float* sbuf = part + (size_t)CHUNK * QLS_HW;
        qls_k1_scan <<<CHUNK * TILES, 1024, 0, stream>>>(x, part);    // 576 blocks
        qls_k2_merge<<<QLS_HW4 / 256, 256, 0, stream>>>(part, sbuf);  // 144 blocks
        qls_k3_out  <<<CHUNK * TILES, 1024, 0, stream>>>(x, sbuf, out); // 576 blocks
    } else {
        qls_fused_kernel<<<QLS_HW / 64, 512, 0, stream>>>(x, out);    // 2304 blocks
    }
}

// Round 9
// 267.650 us; speedup vs baseline: 1.0625x; 1.0625x over previous
//
#include <hip/hip_runtime.h>
#include <math.h>

// Problem constants (x: [4, 64, 384, 384] fp32)
#define QLS_T   256            // B*C = 4*64, sequential scan axis
#define QLS_HW  (384 * 384)    // independent spatial locations
#define CHUNK   8              // parallel t-chunks per location (re-associated scan)
#define TPC     (QLS_T / CHUNK) // 32 planes per chunk

// Quantizer constants from the reference
#define Q_SCALE      16.0f
#define INV_Q_SCALE  (1.0f / 16.0f)
#define QMAXF        7.9375f
#define QMINF        (-8.0f)
#define LUT_IN_SCALE 4096.0f
#define LUT_IN_MAX   32767.0f
#define INV_LUT_OUT  (1.0f / 65536.0f)

// log1p(exp(-d)) = log2(1 + 2^(-d*log2e)) * ln2, on raw v_exp_f32/v_log_f32.
#define NEG_LOG2E_DIV (-1.4426950408889634f / 4096.0f)
#define LN2_X_65536   45426.09375f

__device__ __forceinline__ float qls_step(float s, float v) {
    float diff = fabsf(s - v);
    float d_int = fminf(floorf(diff * LUT_IN_SCALE), LUT_IN_MAX);
    float e  = __builtin_amdgcn_exp2f(d_int * NEG_LOG2E_DIV);
    float lu = rintf(__builtin_amdgcn_logf(1.0f + e) * LN2_X_65536) * INV_LUT_OUT;
    s = fmaxf(s, v) + lu;
    return fminf(fmaxf(s, QMINF), QMAXF);
}

// FINAL (R11 = revert to R7, best measured: 97us dispatch / 266.9us bench).
//
// Structure: 8 t-chunks of 32 planes scanned in parallel (one chunk per
// wave, 512-thread blocks), partials merged in t-order with the SAME
// quantized logaddexp op via LDS (re-association shift ~1e-5 << 1/32 grid
// -> absmax stays at the +-1-step 0.0625). Output quantization fused; the
// compiler re-loads x for the output pass (VGPR=24) and L3 absorbs the
// re-read (FETCH ~74MB < one full x read).
//
// Roofline note (R2-R10 evidence): the scan's 576KB-plane-strided read
// stream caps at ~2.5-3.0 TB/s on MI355X regardless of request width
// (256B/512B/1KB), span size (16KB), time-clustered bursts, occupancy
// (22-64%), MLP depth, or traffic volume -- seven interventions, all
// 97-119us -- while monotone streams hit 6.3-6.6 TB/s (copy/fill). The
// 576KB stride keeps DRAM channel-select bits constant: each location's
// 256 plane-reads serialize on one channel across 256 rows. Floor =
// strided-read ~50us + dependent output pass ~47us ~= 97us; this kernel
// sits on it. A transpose to linearize reads costs 590MB ~= 94us at full
// copy speed -- no gain.
__global__ __launch_bounds__(512, 4) void qls_chunked_kernel(
    const float* __restrict__ x, float* __restrict__ out) {
    const int lane  = threadIdx.x & 63;          // location lane within block
    const int chunk = threadIdx.x >> 6;          // 0..7, one t-chunk per wave
    const int loc   = blockIdx.x * 64 + lane;    // spatial index
    const size_t base = (size_t)loc + (size_t)chunk * TPC * QLS_HW;
    const float* xp = x + base;

    // Load this chunk's 32 planes into registers (coalesced 256B
    // wave-requests; compiler schedules waits per-use).
    float v[TPC];
    #pragma unroll
    for (int k = 0; k < TPC; ++k) v[k] = xp[(size_t)k * QLS_HW];

    // Sequential scan within the chunk (32-step chain, order-preserving).
    float s = QMINF;
    #pragma unroll
    for (int k = 0; k < TPC; ++k) s = qls_step(s, v[k]);

    // Merge the 8 chunk partials in t-order with the same quantized op.
    __shared__ float part[CHUNK][64];
    part[chunk][lane] = s;
    __syncthreads();

    float tot = part[0][lane];
    #pragma unroll
    for (int c = 1; c < CHUNK; ++c) tot = qls_step(tot, part[c][lane]);

    // Output pass: quantize to 1/16 grid, NT store (out never re-read).
    float* op = out + base;
    #pragma unroll
    for (int k = 0; k < TPC; ++k) {
        float q = fminf(fmaxf(rintf((v[k] - tot) * Q_SCALE), -128.0f), 127.0f);
        __builtin_nontemporal_store(q * INV_Q_SCALE, op + (size_t)k * QLS_HW);
    }
}

extern "C" void kernel_launch(void* const* d_in, const int* in_sizes, int n_in,
                              void* d_out, int out_size, void* d_ws, size_t ws_size,
                              hipStream_t stream) {
    const float* x = (const float*)d_in[0];
    float* out = (float*)d_out;
    const int blocks = QLS_HW / 64;  // 2304 blocks x 512 threads
    qls_chunked_kernel<<<blocks, 512, 0, stream>>>(x, out);
}